// Round 1
// baseline (24.779 us; speedup 1.0000x reference)
//
#include <hip/hip_runtime.h>

// Sigma = R * diag(exp(ls))^2 * R^T per gaussian.
// Memory-bound: 28 B in + 36 B out per element, ~128 MB total -> ~20 us floor.

constexpr int BLK = 256;

__global__ __launch_bounds__(BLK) void gauss_covar_kernel(
    const float4* __restrict__ quats,      // [N] (w,x,y,z)
    const float*  __restrict__ log_scales, // [N*3]
    float*        __restrict__ out,        // [N*9]
    int n)
{
    __shared__ float s_scale[BLK * 3];
    __shared__ float s_out[BLK * 9];

    const int tid  = threadIdx.x;
    const int base = blockIdx.x * BLK;

    // ---- cooperative coalesced load of log_scales for this block ----
    const int sbase = base * 3;
    const int slim  = n * 3;
#pragma unroll
    for (int c = 0; c < 3; ++c) {
        int idx = sbase + c * BLK + tid;
        s_scale[c * BLK + tid] = (idx < slim) ? log_scales[idx] : 0.0f;
    }
    __syncthreads();

    const int i = base + tid;
    if (i < n) {
        // quat load: float4, fully coalesced
        float4 q = quats[i];
        float w = q.x, x = q.y, y = q.z, z = q.w;
        float inv = rsqrtf(fmaf(w, w, fmaf(x, x, fmaf(y, y, z * z))));
        w *= inv; x *= inv; y *= inv; z *= inv;

        // scales (stride-3 LDS read: conflict-free, gcd(3,32)=1)
        float s0 = expf(s_scale[tid * 3 + 0]);
        float s1 = expf(s_scale[tid * 3 + 1]);
        float s2 = expf(s_scale[tid * 3 + 2]);

        // rotation matrix
        float r00 = 1.0f - 2.0f * (y * y + z * z);
        float r01 = 2.0f * (x * y - w * z);
        float r02 = 2.0f * (x * z + w * y);
        float r10 = 2.0f * (x * y + w * z);
        float r11 = 1.0f - 2.0f * (x * x + z * z);
        float r12 = 2.0f * (y * z - w * x);
        float r20 = 2.0f * (x * z - w * y);
        float r21 = 2.0f * (y * z + w * x);
        float r22 = 1.0f - 2.0f * (x * x + y * y);

        // M = R * diag(s)
        float m00 = r00 * s0, m01 = r01 * s1, m02 = r02 * s2;
        float m10 = r10 * s0, m11 = r11 * s1, m12 = r12 * s2;
        float m20 = r20 * s0, m21 = r21 * s1, m22 = r22 * s2;

        // Sigma = M * M^T (symmetric)
        float c00 = fmaf(m00, m00, fmaf(m01, m01, m02 * m02));
        float c01 = fmaf(m00, m10, fmaf(m01, m11, m02 * m12));
        float c02 = fmaf(m00, m20, fmaf(m01, m21, m02 * m22));
        float c11 = fmaf(m10, m10, fmaf(m11, m11, m12 * m12));
        float c12 = fmaf(m10, m20, fmaf(m11, m21, m12 * m22));
        float c22 = fmaf(m20, m20, fmaf(m21, m21, m22 * m22));

        // stride-9 LDS write: conflict-free, gcd(9,32)=1
        float* o = &s_out[tid * 9];
        o[0] = c00; o[1] = c01; o[2] = c02;
        o[3] = c01; o[4] = c11; o[5] = c12;
        o[6] = c02; o[7] = c12; o[8] = c22;
    }
    __syncthreads();

    // ---- cooperative coalesced store of the block's 9*BLK outputs ----
    const int obase = base * 9;
    const int olim  = n * 9;
#pragma unroll
    for (int c = 0; c < 9; ++c) {
        int idx = obase + c * BLK + tid;
        if (idx < olim) out[idx] = s_out[c * BLK + tid];
    }
}

extern "C" void kernel_launch(void* const* d_in, const int* in_sizes, int n_in,
                              void* d_out, int out_size, void* d_ws, size_t ws_size,
                              hipStream_t stream) {
    const float4* quats      = (const float4*)d_in[0];
    const float*  log_scales = (const float*)d_in[1];
    // d_in[2] (logit_opacities) feeds a property that is not returned — skip.
    float* out = (float*)d_out;

    const int n = in_sizes[0] / 4;  // quats is [N,4]
    const int nblocks = (n + BLK - 1) / BLK;
    gauss_covar_kernel<<<nblocks, BLK, 0, stream>>>(quats, log_scales, out, n);
}